// Round 1
// baseline (19.278 us; speedup 1.0000x reference)
//
#include <hip/hip_runtime.h>
#include <math.h>

#define B_  64
#define F_  128
#define CI_ 64
#define CO_ 64
#define R_  4

#define BT   32          // b per block
#define COT  32          // co per block
#define EROW 260         // floats per b-row in LDS: 64*4 + 4 pad (4-bank shift/row)

__global__ __launch_bounds__(256, 2)
void ws_kernel(const float* __restrict__ ll,
               const float* __restrict__ wt,
               float* __restrict__ out)
{
    __shared__ float E[BT * EROW];         // 33280 B : exp(ll - M), [b][ci*4+r] padded
    __shared__ float Wl[CI_ * COT * R_];   // 32768 B : weights tile, [ci][co_local*4+r]
    __shared__ float Msh[BT * R_];         // 512 B   : per-(b,r) max

    const int t   = threadIdx.x;
    const int blk = blockIdx.x;
    const int f   = blk >> 2;
    const int bh  = (blk >> 1) & 1;
    const int ch  = blk & 1;
    const int b0  = bh * BT;
    const int co0 = ch * COT;

    // ---- Phase 1: stage ll tile and W tile into LDS (coalesced float4) ----
    {
        const float4* llv = reinterpret_cast<const float4*>(ll);
        // float4 index of (b,ci) for fixed f: (b*F + f)*64 + ci   (per-b row = 8192 f4)
        #pragma unroll
        for (int k = 0; k < 8; ++k) {
            int idx = (k << 8) + t;              // 0..2047, lane-contiguous per k
            int b   = idx >> 6;
            int ci  = idx & 63;
            float4 v = llv[(size_t)(b0 + b) * (F_ * 64) + (size_t)f * 64 + ci];
            *reinterpret_cast<float4*>(&E[b * EROW + ci * 4]) = v;
        }
        const float4* wv = reinterpret_cast<const float4*>(wt);
        // float4 index of (ci, j): f*4096 + ci*64 + co0 + j
        #pragma unroll
        for (int k = 0; k < 8; ++k) {
            int idx = (k << 8) + t;              // 0..2047
            int ci  = idx >> 5;
            int j   = idx & 31;
            float4 v = wv[(size_t)f * 4096 + ci * 64 + co0 + j];
            *reinterpret_cast<float4*>(&Wl[ci * (COT * R_) + j * 4]) = v;
        }
    }
    __syncthreads();

    // ---- Phase 2: M[b][r] = max_ci ll  (128 threads, 2-way LDS aliasing = free) ----
    if (t < BT * R_) {
        int b = t >> 2, r = t & 3;
        float m = -INFINITY;
        #pragma unroll 8
        for (int ci = 0; ci < CI_; ++ci)
            m = fmaxf(m, E[b * EROW + ci * 4 + r]);
        Msh[t] = m;
    }
    __syncthreads();

    // ---- Phase 3: E = exp2((ll - M) * log2e) in place ----
    {
        const float L2E = 1.44269504088896340736f;
        int b   = t >> 3;                 // fixed per thread
        int cib = (t & 7) << 3;           // 8 consecutive ci
        float4 m4 = *reinterpret_cast<float4*>(&Msh[b * 4]);
        float msx = m4.x * L2E, msy = m4.y * L2E, msz = m4.z * L2E, msw = m4.w * L2E;
        #pragma unroll
        for (int k = 0; k < 8; ++k) {
            float4* p = reinterpret_cast<float4*>(&E[b * EROW + (cib + k) * 4]);
            float4 v = *p;
            v.x = exp2f(fmaf(v.x, L2E, -msx));
            v.y = exp2f(fmaf(v.y, L2E, -msy));
            v.z = exp2f(fmaf(v.z, L2E, -msz));
            v.w = exp2f(fmaf(v.w, L2E, -msw));
            *p = v;
        }
    }
    __syncthreads();

    // ---- Phase 4: register-tiled weighted sum over ci (2b x 2co x float4-r) ----
    const int bp = t >> 4;     // 0..15 -> b_local in {bp, bp+16}
    const int cp = t & 15;     // 0..15 -> co_local in {cp, cp+16}

    float4 a00 = {0,0,0,0}, a01 = {0,0,0,0}, a10 = {0,0,0,0}, a11 = {0,0,0,0};
    const float4* e0p = reinterpret_cast<const float4*>(&E[bp * EROW]);
    const float4* e1p = reinterpret_cast<const float4*>(&E[(bp + 16) * EROW]);

    #pragma unroll 4
    for (int ci = 0; ci < CI_; ++ci) {
        float4 e0 = e0p[ci];
        float4 e1 = e1p[ci];
        const float4* wrow = reinterpret_cast<const float4*>(&Wl[ci * (COT * R_)]);
        float4 w0 = wrow[cp];
        float4 w1 = wrow[cp + 16];
        a00.x = fmaf(e0.x, w0.x, a00.x); a00.y = fmaf(e0.y, w0.y, a00.y);
        a00.z = fmaf(e0.z, w0.z, a00.z); a00.w = fmaf(e0.w, w0.w, a00.w);
        a01.x = fmaf(e0.x, w1.x, a01.x); a01.y = fmaf(e0.y, w1.y, a01.y);
        a01.z = fmaf(e0.z, w1.z, a01.z); a01.w = fmaf(e0.w, w1.w, a01.w);
        a10.x = fmaf(e1.x, w0.x, a10.x); a10.y = fmaf(e1.y, w0.y, a10.y);
        a10.z = fmaf(e1.z, w0.z, a10.z); a10.w = fmaf(e1.w, w0.w, a10.w);
        a11.x = fmaf(e1.x, w1.x, a11.x); a11.y = fmaf(e1.y, w1.y, a11.y);
        a11.z = fmaf(e1.z, w1.z, a11.z); a11.w = fmaf(e1.w, w1.w, a11.w);
    }

    // ---- Phase 5: out = log(acc) + M, coalesced float4 stores ----
    const float LN2 = 0.69314718055994530942f;
    float4 m0 = *reinterpret_cast<float4*>(&Msh[bp * 4]);
    float4 m1 = *reinterpret_cast<float4*>(&Msh[(bp + 16) * 4]);

    size_t ob0 = ((size_t)(b0 + bp)      * F_ + f) * (CO_ * R_);
    size_t ob1 = ((size_t)(b0 + bp + 16) * F_ + f) * (CO_ * R_);

    float4 s;
    s.x = fmaf(__log2f(a00.x), LN2, m0.x);
    s.y = fmaf(__log2f(a00.y), LN2, m0.y);
    s.z = fmaf(__log2f(a00.z), LN2, m0.z);
    s.w = fmaf(__log2f(a00.w), LN2, m0.w);
    *reinterpret_cast<float4*>(out + ob0 + (size_t)(co0 + cp) * 4) = s;

    s.x = fmaf(__log2f(a01.x), LN2, m0.x);
    s.y = fmaf(__log2f(a01.y), LN2, m0.y);
    s.z = fmaf(__log2f(a01.z), LN2, m0.z);
    s.w = fmaf(__log2f(a01.w), LN2, m0.w);
    *reinterpret_cast<float4*>(out + ob0 + (size_t)(co0 + cp + 16) * 4) = s;

    s.x = fmaf(__log2f(a10.x), LN2, m1.x);
    s.y = fmaf(__log2f(a10.y), LN2, m1.y);
    s.z = fmaf(__log2f(a10.z), LN2, m1.z);
    s.w = fmaf(__log2f(a10.w), LN2, m1.w);
    *reinterpret_cast<float4*>(out + ob1 + (size_t)(co0 + cp) * 4) = s;

    s.x = fmaf(__log2f(a11.x), LN2, m1.x);
    s.y = fmaf(__log2f(a11.y), LN2, m1.y);
    s.z = fmaf(__log2f(a11.z), LN2, m1.z);
    s.w = fmaf(__log2f(a11.w), LN2, m1.w);
    *reinterpret_cast<float4*>(out + ob1 + (size_t)(co0 + cp + 16) * 4) = s;
}

extern "C" void kernel_launch(void* const* d_in, const int* in_sizes, int n_in,
                              void* d_out, int out_size, void* d_ws, size_t ws_size,
                              hipStream_t stream)
{
    const float* ll = (const float*)d_in[0];
    const float* wt = (const float*)d_in[1];
    float* out = (float*)d_out;
    // grid: 128 f * 2 b-halves * 2 co-halves = 512 blocks (2 per CU)
    hipLaunchKernelGGL(ws_kernel, dim3(512), dim3(256), 0, stream, ll, wt, out);
}

// Round 2
// 13.189 us; speedup vs baseline: 1.4616x; 1.4616x over previous
//
#include <hip/hip_runtime.h>
#include <math.h>

typedef __attribute__((ext_vector_type(8))) short short8;   // 8 x bf16 (4 VGPR)
typedef __attribute__((ext_vector_type(4))) float f32x4;

#define L2E 1.44269504088896340736f
#define LN2 0.69314718055994530942f

// round-to-nearest-even float -> bf16 bits
static __device__ __forceinline__ unsigned int bfr(float x) {
    union { float f; unsigned u; } v; v.f = x;
    return (v.u + 0x7fffu + ((v.u >> 16) & 1u)) >> 16;
}
static __device__ __forceinline__ unsigned int pk2(float lo, float hi) {
    return bfr(lo) | (bfr(hi) << 16);
}

// out[b,f,co,r] = log( sum_ci w[f,ci,co,r] * exp(ll[b,f,ci,r]) )
// grid 512 = f(128) x b-half(2) x co-half(2); block 256 = 4 waves; wave w handles r=w.
__global__ __launch_bounds__(256, 2)
void ws_kernel(const float* __restrict__ ll,
               const float* __restrict__ wt,
               float* __restrict__ out)
{
    // bf16 operand tiles, [r][row][ci=64], 128B rows, XOR-swizzled ((row&7)<<4)
    __shared__ unsigned short Elds[4 * 32 * 64];   // 16 KB: E[r][b_local][ci]
    __shared__ unsigned short Wlds[4 * 32 * 64];   // 16 KB: Wt[r][co_local][ci]

    const int t   = threadIdx.x;
    const int blk = blockIdx.x;
    const int f   = blk >> 2;
    const int b0  = ((blk >> 1) & 1) * 32;
    const int co0 = (blk & 1) * 32;

    char* Ebase = (char*)Elds;
    char* Wbase = (char*)Wlds;

    // ---- stage E = bf16(exp(ll)) : thread owns (b, ci-pair) ----
    {
        const float4* llv = (const float4*)ll;
        const int c  = t & 31;           // ci = 2c, 2c+1
        const int bb = t >> 5;           // 0..7
        #pragma unroll
        for (int k = 0; k < 4; ++k) {
            const int b = bb + 8 * k;    // 0..31
            const size_t base = (size_t)(b0 + b) * 8192 + (size_t)f * 64 + 2 * c;
            float4 v0 = llv[base];       // r = 0..3 of ci=2c
            float4 v1 = llv[base + 1];   // r = 0..3 of ci=2c+1
            float e0x = exp2f(v0.x * L2E), e0y = exp2f(v0.y * L2E),
                  e0z = exp2f(v0.z * L2E), e0w = exp2f(v0.w * L2E);
            float e1x = exp2f(v1.x * L2E), e1y = exp2f(v1.y * L2E),
                  e1z = exp2f(v1.z * L2E), e1w = exp2f(v1.w * L2E);
            const int off = (c * 4) ^ ((b & 7) << 4);
            char* rowp = Ebase + b * 128 + off;
            *(unsigned*)(rowp)         = pk2(e0x, e1x);   // r=0 plane
            *(unsigned*)(rowp + 4096)  = pk2(e0y, e1y);   // r=1
            *(unsigned*)(rowp + 8192)  = pk2(e0z, e1z);   // r=2
            *(unsigned*)(rowp + 12288) = pk2(e0w, e1w);   // r=3
        }
    }
    // ---- stage Wt = bf16(w) transposed to [co][ci] : thread owns (co, ci-quad) ----
    {
        const float4* wv = (const float4*)wt;
        const int j = t & 31;            // co_local
        #pragma unroll
        for (int k = 0; k < 2; ++k) {
            const int cq = (t >> 5) + 8 * k;     // 0..15 ; ci = 4cq + i
            const size_t base = (size_t)f * 4096 + (size_t)(4 * cq) * 64 + co0 + j;
            float4 q0 = wv[base];
            float4 q1 = wv[base + 64];
            float4 q2 = wv[base + 128];
            float4 q3 = wv[base + 192];
            const int off = (cq * 8) ^ ((j & 7) << 4);
            char* rowp = Wbase + j * 128 + off;
            *(uint2*)(rowp)         = make_uint2(pk2(q0.x, q1.x), pk2(q2.x, q3.x));
            *(uint2*)(rowp + 4096)  = make_uint2(pk2(q0.y, q1.y), pk2(q2.y, q3.y));
            *(uint2*)(rowp + 8192)  = make_uint2(pk2(q0.z, q1.z), pk2(q2.z, q3.z));
            *(uint2*)(rowp + 12288) = make_uint2(pk2(q0.w, q1.w), pk2(q2.w, q3.w));
        }
    }
    __syncthreads();

    // ---- MFMA: wave r computes C[32b x 32co] = E_r(32x64) . Wt_r^T(64x32) ----
    const int r  = t >> 6;
    const int l  = t & 63;
    const int lr = l & 15;     // A-row / B-col within 16-tile
    const int lg = l >> 4;     // k-group (8 contiguous k each)
    const char* Ep = Ebase + r * 4096;
    const char* Wp = Wbase + r * 4096;

    f32x4 acc[2][2] = {{{0.f,0.f,0.f,0.f},{0.f,0.f,0.f,0.f}},
                       {{0.f,0.f,0.f,0.f},{0.f,0.f,0.f,0.f}}};
    const int swz = (lr & 7) << 4;   // (row&7)<<4 ; (lr+16)&7 == lr&7
    #pragma unroll
    for (int kt = 0; kt < 2; ++kt) {
        const int sb = ((kt * 4 + lg) * 16) ^ swz;   // byte offset of 16B chunk in row
        short8 a0 = *(const short8*)(Ep + lr * 128 + sb);
        short8 a1 = *(const short8*)(Ep + (lr + 16) * 128 + sb);
        short8 w0 = *(const short8*)(Wp + lr * 128 + sb);
        short8 w1 = *(const short8*)(Wp + (lr + 16) * 128 + sb);
        acc[0][0] = __builtin_amdgcn_mfma_f32_16x16x32_bf16(a0, w0, acc[0][0], 0, 0, 0);
        acc[0][1] = __builtin_amdgcn_mfma_f32_16x16x32_bf16(a0, w1, acc[0][1], 0, 0, 0);
        acc[1][0] = __builtin_amdgcn_mfma_f32_16x16x32_bf16(a1, w0, acc[1][0], 0, 0, 0);
        acc[1][1] = __builtin_amdgcn_mfma_f32_16x16x32_bf16(a1, w1, acc[1][1], 0, 0, 0);
    }

    // ---- epilogue: out = log(acc), direct stores ----
    // D layout (verified m89): col = l&15, row = (l>>4)*4 + v
    float* op = out + ((size_t)b0 * 128 + f) * 256 + (size_t)(co0 + lr) * 4 + r;
    #pragma unroll
    for (int mt = 0; mt < 2; ++mt) {
        #pragma unroll
        for (int v = 0; v < 4; ++v) {
            const size_t bl = (size_t)(mt * 16 + lg * 4 + v) * 32768;  // b stride = F*CO*R
            op[bl]      = __log2f(acc[mt][0][v]) * LN2;
            op[bl + 64] = __log2f(acc[mt][1][v]) * LN2;   // +16 co = 64 floats
        }
    }
}

extern "C" void kernel_launch(void* const* d_in, const int* in_sizes, int n_in,
                              void* d_out, int out_size, void* d_ws, size_t ws_size,
                              hipStream_t stream)
{
    const float* ll = (const float*)d_in[0];
    const float* wt = (const float*)d_in[1];
    float* out = (float*)d_out;
    hipLaunchKernelGGL(ws_kernel, dim3(512), dim3(256), 0, stream, ll, wt, out);
}